// Round 8
// baseline (224.953 us; speedup 1.0000x reference)
//
#include <hip/hip_runtime.h>
#include <math.h>

// Exact IEEE semantics in the visibility path: no fma contraction anywhere.
#pragma clang fp contract(off)

#define IMG 128
#define HW (IMG * IMG)
#define NB 2
#define NV 1300
#define NF 2500
#define NFACE (NB * NF) // 5000
#define EPSF 1e-8f
#define NTILE 256       // 16x16 grid of 8x8-px tiles per batch
#define NBIN (NB * NTILE)
#define MAXBIN 2500     // absolute max faces per bin
#define KLAY 16         // depth layers per tile (waves per bin)

// ws layout (bytes):
//   vn    f32[NB*NV*3]        @ 0        (31200)  zeroed by memset
//   bcnt  u32[NBIN]           @ 31232    (2048)   zeroed by memset
//   face  f4 [NFACE*3]        @ 33280    (240000) {E0, E1, {area,z0,z1,z2}}
//   bins  u32[NBIN][MAXBIN]   @ 273280   (5.12MB) face ids (per batch)
//   dbuf  u64[KLAY][NB][NTILE][64] @ 5393280 (4MB) per-layer best, no init
#define OFF_BCNT 31232
#define OFF_FACE 33280
#define OFF_BINS 273280
#define OFF_DBUF 5393280

#define DINIT 0x7F800000FFFFFFFFull // depth=+inf, fidx=~0

__global__ __launch_bounds__(256) void k_face(const float* __restrict__ verts,
                                              const int* __restrict__ faces,
                                              float* __restrict__ vn,
                                              float4* __restrict__ face,
                                              unsigned* __restrict__ bcnt,
                                              unsigned* __restrict__ bins) {
    int i = blockIdx.x * 256 + threadIdx.x;
    if (i >= NFACE) return;
    int b = (i >= NF) ? 1 : 0;
    int f = i - b * NF;
    int i0 = faces[f * 3 + 0];
    int i1 = faces[f * 3 + 1];
    int i2 = faces[f * 3 + 2];
    const float* wv = verts + (size_t)b * NV * 3;
    float v0x = wv[i0 * 3 + 0], v0y = wv[i0 * 3 + 1], v0z = wv[i0 * 3 + 2];
    float v1x = wv[i1 * 3 + 0], v1y = wv[i1 * 3 + 1], v1z = wv[i1 * 3 + 2];
    float v2x = wv[i2 * 3 + 0], v2y = wv[i2 * 3 + 1], v2z = wv[i2 * 3 + 2];
    // transform, bit-identical to ref: ndc = (12*(-vx))/(2-vz), z = 2-vz
    float z0 = 2.0f - v0z, z1 = 2.0f - v1z, z2 = 2.0f - v2z;
    float p0x = (12.0f * (-v0x)) / z0, p0y = (12.0f * v0y) / z0;
    float p1x = (12.0f * (-v1x)) / z1, p1y = (12.0f * v1y) / z1;
    float p2x = (12.0f * (-v2x)) / z2, p2y = (12.0f * v2y) / z2;

    float t1 = (p1x - p0x) * (p2y - p0y);
    float t2 = (p1y - p0y) * (p2x - p0x);
    float area = t1 - t2;
    float aabs = fabsf(area);
    float area_safe = (aabs < EPSF) ? EPSF : area;

    float E0x = p2x - p1x, E0y = p2y - p1y, E0z = p1x, E0w = p1y;
    float E1x = p0x - p2x, E1y = p0y - p2y, E1z = p2x, E1w = p2y;
    face[i * 3 + 0] = make_float4(E0x, E0y, E0z, E0w);
    face[i * 3 + 1] = make_float4(E1x, E1y, E1z, E1w);
    face[i * 3 + 2] = make_float4(area_safe, z0, z1, z2);

    // world-space face normal -> scatter to vertex normals
    {
        float ax = v1x - v0x, ay = v1y - v0y, az = v1z - v0z;
        float bx = v2x - v0x, by = v2y - v0y, bz = v2z - v0z;
        float fnx = ay * bz - az * by;
        float fny = az * bx - ax * bz;
        float fnz = ax * by - ay * bx;
        float* vnb = vn + (size_t)b * NV * 3;
        atomicAdd(&vnb[i0 * 3 + 0], fnx);
        atomicAdd(&vnb[i0 * 3 + 1], fny);
        atomicAdd(&vnb[i0 * 3 + 2], fnz);
        atomicAdd(&vnb[i1 * 3 + 0], fnx);
        atomicAdd(&vnb[i1 * 3 + 1], fny);
        atomicAdd(&vnb[i1 * 3 + 2], fnz);
        atomicAdd(&vnb[i2 * 3 + 0], fnx);
        atomicAdd(&vnb[i2 * 3 + 1], fny);
        atomicAdd(&vnb[i2 * 3 + 2], fnz);
    }

    if (aabs <= EPSF) return; // never visible (ref requires |area| > EPS)

    float minx = fminf(p0x, fminf(p1x, p2x));
    float maxx = fmaxf(p0x, fmaxf(p1x, p2x));
    float miny = fminf(p0y, fminf(p1y, p2y));
    float maxy = fmaxf(p0y, fmaxf(p1y, p2y));
    // pixel c: px = 1-(2c+1)/128 (decreasing); c(px=X) = (1-X)*64-0.5; +-1 slack
    int ci0 = (int)floorf((1.0f - maxx) * 64.0f - 0.5f) - 1;
    int ci1 = (int)floorf((1.0f - minx) * 64.0f - 0.5f) + 1;
    int ri0 = (int)floorf((1.0f - maxy) * 64.0f - 0.5f) - 1;
    int ri1 = (int)floorf((1.0f - miny) * 64.0f - 0.5f) + 1;
    if (ci1 < 0 || ci0 > 127 || ri1 < 0 || ri0 > 127) return;
    int cmin = max(ci0, 0), cmax = min(ci1, 127);
    int rmin = max(ri0, 0), rmax = min(ri1, 127);

    float s = (area_safe > 0.0f) ? 1.0f : -1.0f;
    // conservative SAT margins (fp error is ~1e-6 * magnitude; 1e-3 is safe)
    float mg0 = 1e-3f * (1.0f + fabsf(E0x) + fabsf(E0y));
    float mg1 = 1e-3f * (1.0f + fabsf(E1x) + fabsf(E1y));
    float mg2 = mg0 + mg1 + 1e-6f;
    unsigned* bb = bins + (size_t)(b * NTILE) * MAXBIN;
    unsigned* bc = bcnt + b * NTILE;
    for (int tr = (rmin >> 3); tr <= (rmax >> 3); ++tr) {
        float y_hi = 1.0f - (2.0f * (float)(tr * 8) + 1.0f) / 128.0f;     // max py
        float y_lo = 1.0f - (2.0f * (float)(tr * 8 + 7) + 1.0f) / 128.0f; // min py
        // per-edge y-term extremes: s*Ex*(py-Ew)
        float a0a = s * E0x * (y_lo - E0w), a0b = s * E0x * (y_hi - E0w);
        float max0y = fmaxf(a0a, a0b), min0y = fminf(a0a, a0b);
        float a1a = s * E1x * (y_lo - E1w), a1b = s * E1x * (y_hi - E1w);
        float max1y = fmaxf(a1a, a1b), min1y = fminf(a1a, a1b);
        for (int tc = (cmin >> 3); tc <= (cmax >> 3); ++tc) {
            float x_hi = 1.0f - (2.0f * (float)(tc * 8) + 1.0f) / 128.0f;
            float x_lo = 1.0f - (2.0f * (float)(tc * 8 + 7) + 1.0f) / 128.0f;
            // x-term extremes: -s*Ey*(px-Ez)
            float b0a = -s * E0y * (x_lo - E0z), b0b = -s * E0y * (x_hi - E0z);
            float max0x = fmaxf(b0a, b0b), min0x = fminf(b0a, b0b);
            float b1a = -s * E1y * (x_lo - E1z), b1b = -s * E1y * (x_hi - E1z);
            float max1x = fmaxf(b1a, b1b), min1x = fminf(b1a, b1b);
            // reject tile if any edge provably negative over whole tile
            if (max0y + max0x < -mg0) continue;           // s*e0 < 0 everywhere
            if (max1y + max1x < -mg1) continue;           // s*e1 < 0 everywhere
            float e2max = s * area_safe - (min0y + min0x) - (min1y + min1x);
            if (e2max < -mg2) continue;                   // s*e2 < 0 everywhere
            unsigned slot = atomicAdd(&bc[tr * 16 + tc], 1u);
            bb[(size_t)(tr * 16 + tc) * MAXBIN + slot] = (unsigned)f;
        }
    }
}

// Wave = (tile, layer k). Iterates bin entries k, k+KLAY, ... with
// wave-uniform (scalar) face loads; per-pixel best kept in a register;
// one unconditional 64-lane store at the end. No atomics, no LDS.
__global__ __launch_bounds__(256) void k_raster(const float4* __restrict__ face,
                                                const unsigned* __restrict__ bcnt,
                                                const unsigned* __restrict__ bins,
                                                unsigned long long* __restrict__ dbuf) {
    int id = (blockIdx.x * 1021) & 2047; // odd mult -> bijection, de-correlate CU
    int kq = id & 3;
    int raw = id >> 2;      // 0..511
    int b = raw & 1;
    int tile = raw >> 1;    // 0..255
    int wid = threadIdx.x >> 6;
    int lane = threadIdx.x & 63;
    int k = kq * 4 + wid;
    int bin = b * NTILE + tile;
    int cnt = (int)bcnt[bin];
    const unsigned* bl = bins + (size_t)bin * MAXBIN;

    int r = (tile >> 4) * 8 + (lane >> 3);
    int c = (tile & 15) * 8 + (lane & 7);
    float px = 1.0f - (2.0f * (float)c + 1.0f) / 128.0f;
    float py = 1.0f - (2.0f * (float)r + 1.0f) / 128.0f;

    unsigned long long best = DINIT;
    for (int j = k; j < cnt; j += KLAY) {
        int f = (int)bl[j];
        int i = b * NF + f;
        float4 E0 = face[i * 3 + 0];
        float4 E1 = face[i * 3 + 1];
        float4 FD = face[i * 3 + 2];
        float as = FD.x;
        // exact ref order: e = (bx-ax)*(py-ay) - (by-ay)*(px-ax)
        float u1 = E0.x * (py - E0.w);
        float u2 = E0.y * (px - E0.z);
        float e0 = u1 - u2;
        float u3 = E1.x * (py - E1.w);
        float u4 = E1.y * (px - E1.z);
        float e1 = u3 - u4;
        bool ok = (as > 0.0f) ? (e0 >= 0.0f && e1 >= 0.0f)
                              : (e0 <= 0.0f && e1 <= 0.0f);
        if (__any(ok)) {
            float b0 = e0 / as; // true IEEE division, as in ref
            float b1 = e1 / as;
            float b2 = (1.0f - b0) - b1;
            float S = ((b0 / FD.y) + (b1 / FD.z)) + (b2 / FD.w);
            if (ok && b2 >= 0.0f && S > EPSF) {
                float depth = 1.0f / fmaxf(S, EPSF);
                unsigned long long pk =
                    ((unsigned long long)__float_as_uint(depth) << 32) | (unsigned)f;
                if (pk < best) best = pk;
            }
        }
    }
    dbuf[(((size_t)k * NB + b) * NTILE + tile) * 64 + lane] = best;
}

__global__ __launch_bounds__(256) void k_shade(const float* __restrict__ verts,
                                               const int* __restrict__ faces,
                                               const float* __restrict__ vn,
                                               const unsigned long long* __restrict__ dbuf,
                                               float* __restrict__ out) {
    int i = blockIdx.x * 256 + threadIdx.x; // 0..NB*HW-1
    int b = i >> 14;
    int p = i & (HW - 1);
    int row = p >> 7;
    int col = p & 127;
    int tile = (row >> 3) * 16 + (col >> 3);
    int idx = (row & 7) * 8 + (col & 7);
    unsigned long long pk = DINIT;
    for (int k = 0; k < KLAY; ++k) {
        unsigned long long v = dbuf[(((size_t)k * NB + b) * NTILE + tile) * 64 + idx];
        if (v < pk) pk = v;
    }
    unsigned dbits = (unsigned)(pk >> 32);
    bool hit = dbits < 0x7F800000u;
    float cr = 255.0f, cg = 255.0f, cb = 255.0f, alpha = 0.0f;
    if (hit) {
        alpha = 1.0f;
        int f = (int)(unsigned)(pk & 0xFFFFFFFFull);
        float px = 1.0f - (2.0f * (float)col + 1.0f) / 128.0f;
        float py = 1.0f - (2.0f * (float)row + 1.0f) / 128.0f;
        int i0 = faces[f * 3 + 0];
        int i1 = faces[f * 3 + 1];
        int i2 = faces[f * 3 + 2];
        const float* wv = verts + (size_t)b * NV * 3;
        float v0x = wv[i0 * 3 + 0], v0y = wv[i0 * 3 + 1], v0z = wv[i0 * 3 + 2];
        float v1x = wv[i1 * 3 + 0], v1y = wv[i1 * 3 + 1], v1z = wv[i1 * 3 + 2];
        float v2x = wv[i2 * 3 + 0], v2y = wv[i2 * 3 + 1], v2z = wv[i2 * 3 + 2];
        float z0 = 2.0f - v0z, z1 = 2.0f - v1z, z2 = 2.0f - v2z;
        float a0x = (12.0f * (-v0x)) / z0, a0y = (12.0f * v0y) / z0;
        float a1x = (12.0f * (-v1x)) / z1, a1y = (12.0f * v1y) / z1;
        float a2x = (12.0f * (-v2x)) / z2, a2y = (12.0f * v2y) / z2;

        float t1 = (a1x - a0x) * (a2y - a0y);
        float t2 = (a1y - a0y) * (a2x - a0x);
        float ar = t1 - t2;
        ar = (fabsf(ar) < EPSF) ? EPSF : ar;
        float u1 = (a2x - a1x) * (py - a1y);
        float u2 = (a2y - a1y) * (px - a1x);
        float bb0 = (u1 - u2) / ar;
        float u3 = (a0x - a2x) * (py - a2y);
        float u4 = (a0y - a2y) * (px - a2x);
        float bb1 = (u3 - u4) / ar;
        float bb2 = (1.0f - bb0) - bb1;
        float w0 = bb0 / z0;
        float w1 = bb1 / z1;
        float w2 = bb2 / z2;
        float denom = ((w0 + w1) + w2) + EPSF;
        float pc0 = w0 / denom;
        float pc1 = w1 / denom;
        float pc2 = w2 / denom;

        float posx = (pc0 * v0x + pc1 * v1x) + pc2 * v2x;
        float posy = (pc0 * v0y + pc1 * v1y) + pc2 * v2y;
        float posz = (pc0 * v0z + pc1 * v1z) + pc2 * v2z;

        const float* vnb = vn + (size_t)b * NV * 3;
        float n0x = vnb[i0 * 3 + 0], n0y = vnb[i0 * 3 + 1], n0z = vnb[i0 * 3 + 2];
        float n1x = vnb[i1 * 3 + 0], n1y = vnb[i1 * 3 + 1], n1z = vnb[i1 * 3 + 2];
        float n2x = vnb[i2 * 3 + 0], n2y = vnb[i2 * 3 + 1], n2z = vnb[i2 * 3 + 2];
        float in0 = 1.0f / (sqrtf(n0x * n0x + n0y * n0y + n0z * n0z) + EPSF);
        float in1 = 1.0f / (sqrtf(n1x * n1x + n1y * n1y + n1z * n1z) + EPSF);
        float in2 = 1.0f / (sqrtf(n2x * n2x + n2y * n2y + n2z * n2z) + EPSF);
        n0x *= in0; n0y *= in0; n0z *= in0;
        n1x *= in1; n1y *= in1; n1z *= in1;
        n2x *= in2; n2y *= in2; n2z *= in2;
        float nx = (pc0 * n0x + pc1 * n1x) + pc2 * n2x;
        float ny = (pc0 * n0y + pc1 * n1y) + pc2 * n2y;
        float nz = (pc0 * n0z + pc1 * n1z) + pc2 * n2z;
        float inn = 1.0f / (sqrtf(nx * nx + ny * ny + nz * nz) + EPSF);
        nx *= inn; ny *= inn; nz *= inn;

        float lx = 0.0f - posx, ly = 1.0f - posy, lz = 3.0f - posz;
        float iln = 1.0f / (sqrtf(lx * lx + ly * ly + lz * lz) + EPSF);
        lx *= iln; ly *= iln; lz *= iln;
        float vx = 0.0f - posx, vy = 0.0f - posy, vz = 2.0f - posz;
        float ivn = 1.0f / (sqrtf(vx * vx + vy * vy + vz * vz) + EPSF);
        vx *= ivn; vy *= ivn; vz *= ivn;

        float ndl = nx * lx + ny * ly + nz * lz;
        float ndlr = fmaxf(ndl, 0.0f);
        float rx = 2.0f * ndl * nx - lx;
        float ry = 2.0f * ndl * ny - ly;
        float rz = 2.0f * ndl * nz - lz;
        float sc = fmaxf(rx * vx + ry * vy + rz * vz, 0.0f);
        float spec = 0.2f * 0.6f * powf(sc, 10.0f);
        float shade = 0.5f * 1.0f + 0.3f * 1.0f * ndlr;
        cr = ((142.0f / 255.0f) * shade + spec) * 255.0f;
        cg = ((179.0f / 255.0f) * shade + spec) * 255.0f;
        cb = ((247.0f / 255.0f) * shade + spec) * 255.0f;
    }
    float* img = out + (size_t)b * 3 * HW;
    img[0 * HW + p] = cr;
    img[1 * HW + p] = cg;
    img[2 * HW + p] = cb;
    out[(size_t)NB * 3 * HW + (size_t)b * HW + p] = alpha;
}

extern "C" void kernel_launch(void* const* d_in, const int* in_sizes, int n_in,
                              void* d_out, int out_size, void* d_ws, size_t ws_size,
                              hipStream_t stream) {
    const float* verts = (const float*)d_in[0]; // [NB, NV, 3]
    const int* faces = (const int*)d_in[1];     // [NF, 3]
    char* ws = (char*)d_ws;
    float* vn = (float*)(ws + 0);
    unsigned* bcnt = (unsigned*)(ws + OFF_BCNT);
    float4* face = (float4*)(ws + OFF_FACE);
    unsigned* bins = (unsigned*)(ws + OFF_BINS);
    unsigned long long* dbuf = (unsigned long long*)(ws + OFF_DBUF);
    float* out = (float*)d_out;

    hipMemsetAsync(ws, 0, OFF_FACE, stream); // vn + bcnt
    k_face<<<(NFACE + 255) / 256, 256, 0, stream>>>(verts, faces, vn, face, bcnt, bins);
    k_raster<<<2048, 256, 0, stream>>>(face, bcnt, bins, dbuf);
    k_shade<<<(NB * HW) / 256, 256, 0, stream>>>(verts, faces, vn, dbuf, out);
}

// Round 9
// 138.817 us; speedup vs baseline: 1.6205x; 1.6205x over previous
//
#include <hip/hip_runtime.h>
#include <math.h>

// Exact IEEE semantics in the visibility path: no fma contraction anywhere.
#pragma clang fp contract(off)

#define IMG 128
#define HW (IMG * IMG)
#define NB 2
#define NV 1300
#define NF 2500
#define NFACE (NB * NF) // 5000
#define EPSF 1e-8f
#define NTILE 256       // 16x16 grid of 8x8-px tiles per batch
#define NBIN (NB * NTILE)
#define MAXBIN 2000     // >=3x expected max central-bin load (~650)
#define KLAY 16         // depth layers per tile (waves per bin)

// ws layout (bytes):
//   vn    f32[NB*NV*3]        @ 0        (31200)  zeroed by memset
//   face  f4 [NFACE*3]        @ 31232    (240000) {E0, E1, {area,z0,z1,z2}}
//   bboxf f4 [NFACE]          @ 271232   (80000)  {minx,maxx,miny,maxy}
//   bcnt  u32[NBIN]           @ 351232   (2048)   written by k_bin (no memset)
//   bins  u32[NBIN][MAXBIN]   @ 353280   (4.10MB) face ids (per batch)
//   dbuf  u64[KLAY][NB][NTILE][64] @ 4449280 (4MB) per-layer best, no init
#define OFF_FACE 31232
#define OFF_BBOX 271232
#define OFF_BCNT 351232
#define OFF_BINS 353280
#define OFF_DBUF 4449280

#define DINIT 0x7F800000FFFFFFFFull // depth=+inf, fidx=~0

__global__ __launch_bounds__(256) void k_face(const float* __restrict__ verts,
                                              const int* __restrict__ faces,
                                              float* __restrict__ vn,
                                              float4* __restrict__ face,
                                              float4* __restrict__ bboxf) {
    int i = blockIdx.x * 256 + threadIdx.x;
    if (i >= NFACE) return;
    int b = (i >= NF) ? 1 : 0;
    int f = i - b * NF;
    int i0 = faces[f * 3 + 0];
    int i1 = faces[f * 3 + 1];
    int i2 = faces[f * 3 + 2];
    const float* wv = verts + (size_t)b * NV * 3;
    float v0x = wv[i0 * 3 + 0], v0y = wv[i0 * 3 + 1], v0z = wv[i0 * 3 + 2];
    float v1x = wv[i1 * 3 + 0], v1y = wv[i1 * 3 + 1], v1z = wv[i1 * 3 + 2];
    float v2x = wv[i2 * 3 + 0], v2y = wv[i2 * 3 + 1], v2z = wv[i2 * 3 + 2];
    // transform, bit-identical to ref: ndc = (12*(-vx))/(2-vz), z = 2-vz
    float z0 = 2.0f - v0z, z1 = 2.0f - v1z, z2 = 2.0f - v2z;
    float p0x = (12.0f * (-v0x)) / z0, p0y = (12.0f * v0y) / z0;
    float p1x = (12.0f * (-v1x)) / z1, p1y = (12.0f * v1y) / z1;
    float p2x = (12.0f * (-v2x)) / z2, p2y = (12.0f * v2y) / z2;

    float t1 = (p1x - p0x) * (p2y - p0y);
    float t2 = (p1y - p0y) * (p2x - p0x);
    float area = t1 - t2;
    float aabs = fabsf(area);
    float area_safe = (aabs < EPSF) ? EPSF : area;

    face[i * 3 + 0] = make_float4(p2x - p1x, p2y - p1y, p1x, p1y);
    face[i * 3 + 1] = make_float4(p0x - p2x, p0y - p2y, p2x, p2y);
    face[i * 3 + 2] = make_float4(area_safe, z0, z1, z2);

    if (aabs > EPSF) {
        bboxf[i] = make_float4(fminf(p0x, fminf(p1x, p2x)),
                               fmaxf(p0x, fmaxf(p1x, p2x)),
                               fminf(p0y, fminf(p1y, p2y)),
                               fmaxf(p0y, fmaxf(p1y, p2y)));
    } else {
        bboxf[i] = make_float4(1e30f, -1e30f, 1e30f, -1e30f); // never overlaps
    }

    // world-space face normal -> scatter to vertex normals
    float ax = v1x - v0x, ay = v1y - v0y, az = v1z - v0z;
    float bx = v2x - v0x, by = v2y - v0y, bz = v2z - v0z;
    float fnx = ay * bz - az * by;
    float fny = az * bx - ax * bz;
    float fnz = ax * by - ay * bx;
    float* vnb = vn + (size_t)b * NV * 3;
    atomicAdd(&vnb[i0 * 3 + 0], fnx);
    atomicAdd(&vnb[i0 * 3 + 1], fny);
    atomicAdd(&vnb[i0 * 3 + 2], fnz);
    atomicAdd(&vnb[i1 * 3 + 0], fnx);
    atomicAdd(&vnb[i1 * 3 + 1], fny);
    atomicAdd(&vnb[i1 * 3 + 2], fnz);
    atomicAdd(&vnb[i2 * 3 + 0], fnx);
    atomicAdd(&vnb[i2 * 3 + 1], fny);
    atomicAdd(&vnb[i2 * 3 + 2], fnz);
}

// Tile-stationary binning: one block per bin scans all NF faces of its batch
// (bbox overlap -> SAT), order-preserving ballot-compaction into the bin's
// global list. Zero atomics. SAT margins identical to R8 (proven absmax 0).
__global__ __launch_bounds__(256) void k_bin(const float4* __restrict__ face,
                                             const float4* __restrict__ bboxf,
                                             unsigned* __restrict__ bcnt,
                                             unsigned* __restrict__ bins) {
    __shared__ int wbase[4];
    __shared__ int sbase;
    int bin = blockIdx.x; // 0..NBIN-1
    int b = bin >> 8;
    int tile = bin & 255;
    int tr = tile >> 4, tc = tile & 15;
    float x_hi = 1.0f - (2.0f * (float)(tc * 8) + 1.0f) / 128.0f;
    float x_lo = 1.0f - (2.0f * (float)(tc * 8 + 7) + 1.0f) / 128.0f;
    float y_hi = 1.0f - (2.0f * (float)(tr * 8) + 1.0f) / 128.0f;
    float y_lo = 1.0f - (2.0f * (float)(tr * 8 + 7) + 1.0f) / 128.0f;
    unsigned* bl = bins + (size_t)bin * MAXBIN;
    int t = threadIdx.x, wid = t >> 6, lane = t & 63;
    if (t == 0) sbase = 0;
    __syncthreads();
    for (int base = 0; base < NF; base += 256) {
        int f = base + t;
        bool pass = false;
        if (f < NF) {
            int i = b * NF + f;
            float4 bb = bboxf[i];
            // 0.02 NDC slack (~1.3 px) >> fp error; pixels outside true bbox
            // by more than fp noise can't pass the exact inside test anyway
            if (bb.y >= x_lo - 0.02f && bb.x <= x_hi + 0.02f &&
                bb.w >= y_lo - 0.02f && bb.z <= y_hi + 0.02f) {
                float4 E0 = face[i * 3 + 0];
                float4 E1 = face[i * 3 + 1];
                float as = face[i * 3 + 2].x;
                float s = (as > 0.0f) ? 1.0f : -1.0f;
                float mg0 = 1e-3f * (1.0f + fabsf(E0.x) + fabsf(E0.y));
                float mg1 = 1e-3f * (1.0f + fabsf(E1.x) + fabsf(E1.y));
                float mg2 = mg0 + mg1 + 1e-6f;
                float a0a = s * E0.x * (y_lo - E0.w), a0b = s * E0.x * (y_hi - E0.w);
                float b0a = -s * E0.y * (x_lo - E0.z), b0b = -s * E0.y * (x_hi - E0.z);
                float max0 = fmaxf(a0a, a0b) + fmaxf(b0a, b0b);
                float min0 = fminf(a0a, a0b) + fminf(b0a, b0b);
                float a1a = s * E1.x * (y_lo - E1.w), a1b = s * E1.x * (y_hi - E1.w);
                float b1a = -s * E1.y * (x_lo - E1.z), b1b = -s * E1.y * (x_hi - E1.z);
                float max1 = fmaxf(a1a, a1b) + fmaxf(b1a, b1b);
                float min1 = fminf(a1a, a1b) + fminf(b1a, b1b);
                pass = (max0 >= -mg0) && (max1 >= -mg1) &&
                       ((s * as - min0 - min1) >= -mg2);
            }
        }
        unsigned long long m = __ballot(pass);
        if (lane == 0) wbase[wid] = __popcll(m);
        __syncthreads();
        int myb = sbase;
        for (int w2 = 0; w2 < wid; ++w2) myb += wbase[w2];
        if (pass) {
            int pos = myb + __popcll(m & ((1ull << lane) - 1ull));
            bl[pos] = (unsigned)f;
        }
        __syncthreads();
        if (t == 0) sbase += wbase[0] + wbase[1] + wbase[2] + wbase[3];
        __syncthreads();
    }
    if (t == 0) bcnt[bin] = (unsigned)sbase;
}

// Wave = (tile, layer k). Iterates bin entries k, k+KLAY, ... with
// wave-uniform (scalar) face loads; per-pixel best kept in a register;
// one unconditional 64-lane store at the end. No atomics, no LDS.
__global__ __launch_bounds__(256) void k_raster(const float4* __restrict__ face,
                                                const unsigned* __restrict__ bcnt,
                                                const unsigned* __restrict__ bins,
                                                unsigned long long* __restrict__ dbuf) {
    int id = (blockIdx.x * 1021) & 2047; // odd mult -> bijection, de-correlate CU
    int kq = id & 3;
    int raw = id >> 2;      // 0..511
    int b = raw & 1;
    int tile = raw >> 1;    // 0..255
    int wid = threadIdx.x >> 6;
    int lane = threadIdx.x & 63;
    int k = kq * 4 + wid;
    int bin = b * NTILE + tile;
    int cnt = (int)bcnt[bin];
    const unsigned* bl = bins + (size_t)bin * MAXBIN;

    int r = (tile >> 4) * 8 + (lane >> 3);
    int c = (tile & 15) * 8 + (lane & 7);
    float px = 1.0f - (2.0f * (float)c + 1.0f) / 128.0f;
    float py = 1.0f - (2.0f * (float)r + 1.0f) / 128.0f;

    unsigned long long best = DINIT;
    for (int j = k; j < cnt; j += KLAY) {
        int f = (int)bl[j];
        int i = b * NF + f;
        float4 E0 = face[i * 3 + 0];
        float4 E1 = face[i * 3 + 1];
        float4 FD = face[i * 3 + 2];
        float as = FD.x;
        // exact ref order: e = (bx-ax)*(py-ay) - (by-ay)*(px-ax)
        float u1 = E0.x * (py - E0.w);
        float u2 = E0.y * (px - E0.z);
        float e0 = u1 - u2;
        float u3 = E1.x * (py - E1.w);
        float u4 = E1.y * (px - E1.z);
        float e1 = u3 - u4;
        bool ok = (as > 0.0f) ? (e0 >= 0.0f && e1 >= 0.0f)
                              : (e0 <= 0.0f && e1 <= 0.0f);
        if (__any(ok)) {
            float b0 = e0 / as; // true IEEE division, as in ref
            float b1 = e1 / as;
            float b2 = (1.0f - b0) - b1;
            float S = ((b0 / FD.y) + (b1 / FD.z)) + (b2 / FD.w);
            if (ok && b2 >= 0.0f && S > EPSF) {
                float depth = 1.0f / fmaxf(S, EPSF);
                unsigned long long pk =
                    ((unsigned long long)__float_as_uint(depth) << 32) | (unsigned)f;
                if (pk < best) best = pk;
            }
        }
    }
    dbuf[(((size_t)k * NB + b) * NTILE + tile) * 64 + lane] = best;
}

__global__ __launch_bounds__(256) void k_shade(const float* __restrict__ verts,
                                               const int* __restrict__ faces,
                                               const float* __restrict__ vn,
                                               const unsigned long long* __restrict__ dbuf,
                                               float* __restrict__ out) {
    int i = blockIdx.x * 256 + threadIdx.x; // 0..NB*HW-1
    int b = i >> 14;
    int p = i & (HW - 1);
    int row = p >> 7;
    int col = p & 127;
    int tile = (row >> 3) * 16 + (col >> 3);
    int idx = (row & 7) * 8 + (col & 7);
    unsigned long long pk = DINIT;
    for (int k = 0; k < KLAY; ++k) {
        unsigned long long v = dbuf[(((size_t)k * NB + b) * NTILE + tile) * 64 + idx];
        if (v < pk) pk = v;
    }
    unsigned dbits = (unsigned)(pk >> 32);
    bool hit = dbits < 0x7F800000u;
    float cr = 255.0f, cg = 255.0f, cb = 255.0f, alpha = 0.0f;
    if (hit) {
        alpha = 1.0f;
        int f = (int)(unsigned)(pk & 0xFFFFFFFFull);
        float px = 1.0f - (2.0f * (float)col + 1.0f) / 128.0f;
        float py = 1.0f - (2.0f * (float)row + 1.0f) / 128.0f;
        int i0 = faces[f * 3 + 0];
        int i1 = faces[f * 3 + 1];
        int i2 = faces[f * 3 + 2];
        const float* wv = verts + (size_t)b * NV * 3;
        float v0x = wv[i0 * 3 + 0], v0y = wv[i0 * 3 + 1], v0z = wv[i0 * 3 + 2];
        float v1x = wv[i1 * 3 + 0], v1y = wv[i1 * 3 + 1], v1z = wv[i1 * 3 + 2];
        float v2x = wv[i2 * 3 + 0], v2y = wv[i2 * 3 + 1], v2z = wv[i2 * 3 + 2];
        float z0 = 2.0f - v0z, z1 = 2.0f - v1z, z2 = 2.0f - v2z;
        float a0x = (12.0f * (-v0x)) / z0, a0y = (12.0f * v0y) / z0;
        float a1x = (12.0f * (-v1x)) / z1, a1y = (12.0f * v1y) / z1;
        float a2x = (12.0f * (-v2x)) / z2, a2y = (12.0f * v2y) / z2;

        float t1 = (a1x - a0x) * (a2y - a0y);
        float t2 = (a1y - a0y) * (a2x - a0x);
        float ar = t1 - t2;
        ar = (fabsf(ar) < EPSF) ? EPSF : ar;
        float u1 = (a2x - a1x) * (py - a1y);
        float u2 = (a2y - a1y) * (px - a1x);
        float bb0 = (u1 - u2) / ar;
        float u3 = (a0x - a2x) * (py - a2y);
        float u4 = (a0y - a2y) * (px - a2x);
        float bb1 = (u3 - u4) / ar;
        float bb2 = (1.0f - bb0) - bb1;
        float w0 = bb0 / z0;
        float w1 = bb1 / z1;
        float w2 = bb2 / z2;
        float denom = ((w0 + w1) + w2) + EPSF;
        float pc0 = w0 / denom;
        float pc1 = w1 / denom;
        float pc2 = w2 / denom;

        float posx = (pc0 * v0x + pc1 * v1x) + pc2 * v2x;
        float posy = (pc0 * v0y + pc1 * v1y) + pc2 * v2y;
        float posz = (pc0 * v0z + pc1 * v1z) + pc2 * v2z;

        const float* vnb = vn + (size_t)b * NV * 3;
        float n0x = vnb[i0 * 3 + 0], n0y = vnb[i0 * 3 + 1], n0z = vnb[i0 * 3 + 2];
        float n1x = vnb[i1 * 3 + 0], n1y = vnb[i1 * 3 + 1], n1z = vnb[i1 * 3 + 2];
        float n2x = vnb[i2 * 3 + 0], n2y = vnb[i2 * 3 + 1], n2z = vnb[i2 * 3 + 2];
        float in0 = 1.0f / (sqrtf(n0x * n0x + n0y * n0y + n0z * n0z) + EPSF);
        float in1 = 1.0f / (sqrtf(n1x * n1x + n1y * n1y + n1z * n1z) + EPSF);
        float in2 = 1.0f / (sqrtf(n2x * n2x + n2y * n2y + n2z * n2z) + EPSF);
        n0x *= in0; n0y *= in0; n0z *= in0;
        n1x *= in1; n1y *= in1; n1z *= in1;
        n2x *= in2; n2y *= in2; n2z *= in2;
        float nx = (pc0 * n0x + pc1 * n1x) + pc2 * n2x;
        float ny = (pc0 * n0y + pc1 * n1y) + pc2 * n2y;
        float nz = (pc0 * n0z + pc1 * n1z) + pc2 * n2z;
        float inn = 1.0f / (sqrtf(nx * nx + ny * ny + nz * nz) + EPSF);
        nx *= inn; ny *= inn; nz *= inn;

        float lx = 0.0f - posx, ly = 1.0f - posy, lz = 3.0f - posz;
        float iln = 1.0f / (sqrtf(lx * lx + ly * ly + lz * lz) + EPSF);
        lx *= iln; ly *= iln; lz *= iln;
        float vx = 0.0f - posx, vy = 0.0f - posy, vz = 2.0f - posz;
        float ivn = 1.0f / (sqrtf(vx * vx + vy * vy + vz * vz) + EPSF);
        vx *= ivn; vy *= ivn; vz *= ivn;

        float ndl = nx * lx + ny * ly + nz * lz;
        float ndlr = fmaxf(ndl, 0.0f);
        float rx = 2.0f * ndl * nx - lx;
        float ry = 2.0f * ndl * ny - ly;
        float rz = 2.0f * ndl * nz - lz;
        float sc = fmaxf(rx * vx + ry * vy + rz * vz, 0.0f);
        float spec = 0.2f * 0.6f * powf(sc, 10.0f);
        float shade = 0.5f * 1.0f + 0.3f * 1.0f * ndlr;
        cr = ((142.0f / 255.0f) * shade + spec) * 255.0f;
        cg = ((179.0f / 255.0f) * shade + spec) * 255.0f;
        cb = ((247.0f / 255.0f) * shade + spec) * 255.0f;
    }
    float* img = out + (size_t)b * 3 * HW;
    img[0 * HW + p] = cr;
    img[1 * HW + p] = cg;
    img[2 * HW + p] = cb;
    out[(size_t)NB * 3 * HW + (size_t)b * HW + p] = alpha;
}

extern "C" void kernel_launch(void* const* d_in, const int* in_sizes, int n_in,
                              void* d_out, int out_size, void* d_ws, size_t ws_size,
                              hipStream_t stream) {
    const float* verts = (const float*)d_in[0]; // [NB, NV, 3]
    const int* faces = (const int*)d_in[1];     // [NF, 3]
    char* ws = (char*)d_ws;
    float* vn = (float*)(ws + 0);
    float4* face = (float4*)(ws + OFF_FACE);
    float4* bboxf = (float4*)(ws + OFF_BBOX);
    unsigned* bcnt = (unsigned*)(ws + OFF_BCNT);
    unsigned* bins = (unsigned*)(ws + OFF_BINS);
    unsigned long long* dbuf = (unsigned long long*)(ws + OFF_DBUF);
    float* out = (float*)d_out;

    hipMemsetAsync(ws, 0, OFF_FACE, stream); // vn
    k_face<<<(NFACE + 255) / 256, 256, 0, stream>>>(verts, faces, vn, face, bboxf);
    k_bin<<<NBIN, 256, 0, stream>>>(face, bboxf, bcnt, bins);
    k_raster<<<2048, 256, 0, stream>>>(face, bcnt, bins, dbuf);
    k_shade<<<(NB * HW) / 256, 256, 0, stream>>>(verts, faces, vn, dbuf, out);
}

// Round 10
// 107.040 us; speedup vs baseline: 2.1016x; 1.2969x over previous
//
#include <hip/hip_runtime.h>
#include <math.h>

// Exact IEEE semantics in the visibility path: no fma contraction anywhere.
#pragma clang fp contract(off)

#define IMG 128
#define HW (IMG * IMG)
#define NB 2
#define NV 1300
#define NF 2500
#define NFACE (NB * NF) // 5000
#define EPSF 1e-8f
#define NTILE 256       // 16x16 grid of 8x8-px tiles per batch
#define NBIN (NB * NTILE)
#define MAXBIN 2000     // proven sufficient in R9 (absmax 0)
#define TASKQ 32        // bin entries per task
#define MAXTASK (NBIN * ((NF + TASKQ - 1) / TASKQ)) // worst-case bound
#define NWAVE 8192      // raster waves (2048 blocks x 4)

// ws layout (bytes):
//   vn    f32[NB*NV*3]        @ 0        (31200)  zeroed by memset
//   ntask u32                 @ 31232    (4)      zeroed by memset
//   face  f4 [NFACE*3]        @ 31744    (240000) {E0, E1, {area,z0,z1,z2}}
//   bboxf f4 [NFACE]          @ 271744   (80000)  {minx,maxx,miny,maxy}
//   tasks u32[MAXTASK]        @ 351744   (161792) bin<<18 | j0<<6 | len
//   bins  u32[NBIN][MAXBIN]   @ 513536   (4.10MB) face ids (per batch)
//   dbuf  u64[NBIN][64]       @ 4609536  (256KB)  memset 0xFF
#define OFF_NTASK 31232
#define OFF_FACE 31744
#define OFF_BBOX 271744
#define OFF_TASK 351744
#define OFF_BINS 513536
#define OFF_DBUF 4609536

#define DINIT 0x7F800000FFFFFFFFull // depth=+inf, fidx=~0

__global__ __launch_bounds__(256) void k_face(const float* __restrict__ verts,
                                              const int* __restrict__ faces,
                                              float* __restrict__ vn,
                                              float4* __restrict__ face,
                                              float4* __restrict__ bboxf) {
    int i = blockIdx.x * 256 + threadIdx.x;
    if (i >= NFACE) return;
    int b = (i >= NF) ? 1 : 0;
    int f = i - b * NF;
    int i0 = faces[f * 3 + 0];
    int i1 = faces[f * 3 + 1];
    int i2 = faces[f * 3 + 2];
    const float* wv = verts + (size_t)b * NV * 3;
    float v0x = wv[i0 * 3 + 0], v0y = wv[i0 * 3 + 1], v0z = wv[i0 * 3 + 2];
    float v1x = wv[i1 * 3 + 0], v1y = wv[i1 * 3 + 1], v1z = wv[i1 * 3 + 2];
    float v2x = wv[i2 * 3 + 0], v2y = wv[i2 * 3 + 1], v2z = wv[i2 * 3 + 2];
    // transform, bit-identical to ref: ndc = (12*(-vx))/(2-vz), z = 2-vz
    float z0 = 2.0f - v0z, z1 = 2.0f - v1z, z2 = 2.0f - v2z;
    float p0x = (12.0f * (-v0x)) / z0, p0y = (12.0f * v0y) / z0;
    float p1x = (12.0f * (-v1x)) / z1, p1y = (12.0f * v1y) / z1;
    float p2x = (12.0f * (-v2x)) / z2, p2y = (12.0f * v2y) / z2;

    float t1 = (p1x - p0x) * (p2y - p0y);
    float t2 = (p1y - p0y) * (p2x - p0x);
    float area = t1 - t2;
    float aabs = fabsf(area);
    float area_safe = (aabs < EPSF) ? EPSF : area;

    face[i * 3 + 0] = make_float4(p2x - p1x, p2y - p1y, p1x, p1y);
    face[i * 3 + 1] = make_float4(p0x - p2x, p0y - p2y, p2x, p2y);
    face[i * 3 + 2] = make_float4(area_safe, z0, z1, z2);

    if (aabs > EPSF) {
        bboxf[i] = make_float4(fminf(p0x, fminf(p1x, p2x)),
                               fmaxf(p0x, fmaxf(p1x, p2x)),
                               fminf(p0y, fminf(p1y, p2y)),
                               fmaxf(p0y, fmaxf(p1y, p2y)));
    } else {
        bboxf[i] = make_float4(1e30f, -1e30f, 1e30f, -1e30f); // never overlaps
    }

    // world-space face normal -> scatter to vertex normals
    float ax = v1x - v0x, ay = v1y - v0y, az = v1z - v0z;
    float bx = v2x - v0x, by = v2y - v0y, bz = v2z - v0z;
    float fnx = ay * bz - az * by;
    float fny = az * bx - ax * bz;
    float fnz = ax * by - ay * bx;
    float* vnb = vn + (size_t)b * NV * 3;
    atomicAdd(&vnb[i0 * 3 + 0], fnx);
    atomicAdd(&vnb[i0 * 3 + 1], fny);
    atomicAdd(&vnb[i0 * 3 + 2], fnz);
    atomicAdd(&vnb[i1 * 3 + 0], fnx);
    atomicAdd(&vnb[i1 * 3 + 1], fny);
    atomicAdd(&vnb[i1 * 3 + 2], fnz);
    atomicAdd(&vnb[i2 * 3 + 0], fnx);
    atomicAdd(&vnb[i2 * 3 + 1], fny);
    atomicAdd(&vnb[i2 * 3 + 2], fnz);
}

// Tile-stationary binning (R9-proven SAT), plus equal-size task emission:
// each bin appends ceil(cnt/32) tasks with ONE global atomicAdd.
__global__ __launch_bounds__(256) void k_bin(const float4* __restrict__ face,
                                             const float4* __restrict__ bboxf,
                                             unsigned* __restrict__ bins,
                                             unsigned* __restrict__ tasks,
                                             unsigned* __restrict__ ntask) {
    __shared__ int wbase[4];
    __shared__ int sbase;
    __shared__ int tbase;
    int bin = blockIdx.x; // 0..NBIN-1
    int b = bin >> 8;
    int tile = bin & 255;
    int tr = tile >> 4, tc = tile & 15;
    float x_hi = 1.0f - (2.0f * (float)(tc * 8) + 1.0f) / 128.0f;
    float x_lo = 1.0f - (2.0f * (float)(tc * 8 + 7) + 1.0f) / 128.0f;
    float y_hi = 1.0f - (2.0f * (float)(tr * 8) + 1.0f) / 128.0f;
    float y_lo = 1.0f - (2.0f * (float)(tr * 8 + 7) + 1.0f) / 128.0f;
    unsigned* bl = bins + (size_t)bin * MAXBIN;
    int t = threadIdx.x, wid = t >> 6, lane = t & 63;
    if (t == 0) sbase = 0;
    __syncthreads();
    for (int base = 0; base < NF; base += 256) {
        int f = base + t;
        bool pass = false;
        if (f < NF) {
            int i = b * NF + f;
            float4 bb = bboxf[i];
            if (bb.y >= x_lo - 0.02f && bb.x <= x_hi + 0.02f &&
                bb.w >= y_lo - 0.02f && bb.z <= y_hi + 0.02f) {
                float4 E0 = face[i * 3 + 0];
                float4 E1 = face[i * 3 + 1];
                float as = face[i * 3 + 2].x;
                float s = (as > 0.0f) ? 1.0f : -1.0f;
                float mg0 = 1e-3f * (1.0f + fabsf(E0.x) + fabsf(E0.y));
                float mg1 = 1e-3f * (1.0f + fabsf(E1.x) + fabsf(E1.y));
                float mg2 = mg0 + mg1 + 1e-6f;
                float a0a = s * E0.x * (y_lo - E0.w), a0b = s * E0.x * (y_hi - E0.w);
                float b0a = -s * E0.y * (x_lo - E0.z), b0b = -s * E0.y * (x_hi - E0.z);
                float max0 = fmaxf(a0a, a0b) + fmaxf(b0a, b0b);
                float min0 = fminf(a0a, a0b) + fminf(b0a, b0b);
                float a1a = s * E1.x * (y_lo - E1.w), a1b = s * E1.x * (y_hi - E1.w);
                float b1a = -s * E1.y * (x_lo - E1.z), b1b = -s * E1.y * (x_hi - E1.z);
                float max1 = fmaxf(a1a, a1b) + fmaxf(b1a, b1b);
                float min1 = fminf(a1a, a1b) + fminf(b1a, b1b);
                pass = (max0 >= -mg0) && (max1 >= -mg1) &&
                       ((s * as - min0 - min1) >= -mg2);
            }
        }
        unsigned long long m = __ballot(pass);
        if (lane == 0) wbase[wid] = __popcll(m);
        __syncthreads();
        int myb = sbase;
        for (int w2 = 0; w2 < wid; ++w2) myb += wbase[w2];
        if (pass) {
            int pos = myb + __popcll(m & ((1ull << lane) - 1ull));
            bl[pos] = (unsigned)f;
        }
        __syncthreads();
        if (t == 0) sbase += wbase[0] + wbase[1] + wbase[2] + wbase[3];
        __syncthreads();
    }
    int cnt = sbase;
    int nt = (cnt + TASKQ - 1) / TASKQ;
    if (t == 0 && nt > 0) tbase = (int)atomicAdd(ntask, (unsigned)nt);
    __syncthreads();
    if (t < nt) {
        int j0 = t * TASKQ;
        int len = min(TASKQ, cnt - j0);
        tasks[tbase + t] = ((unsigned)bin << 18) | ((unsigned)j0 << 6) | (unsigned)len;
    }
}

// Persistent waves over equal-size tasks. Per task: 32 face ids loaded
// coalesced once, broadcast via shfl; face data double-buffered one
// iteration ahead; merge via u64 atomicMin (exact: min-order-independent,
// tie -> lowest face idx).
__global__ __launch_bounds__(256) void k_raster(const float4* __restrict__ face,
                                                const unsigned* __restrict__ bins,
                                                const unsigned* __restrict__ tasks,
                                                const unsigned* __restrict__ ntask,
                                                unsigned long long* __restrict__ dbuf) {
    int lane = threadIdx.x & 63;
    int wave = blockIdx.x * 4 + (threadIdx.x >> 6);
    int n = (int)*ntask;
    for (int t = wave; t < n; t += NWAVE) {
        unsigned tk = tasks[t];
        int bin = (int)(tk >> 18);
        int j0 = (int)((tk >> 6) & 0xFFFu);
        int len = (int)(tk & 63u);
        int b = bin >> 8;
        int tile = bin & 255;
        const unsigned* bl = bins + (size_t)bin * MAXBIN;
        int r = (tile >> 4) * 8 + (lane >> 3);
        int c = (tile & 15) * 8 + (lane & 7);
        float px = 1.0f - (2.0f * (float)c + 1.0f) / 128.0f;
        float py = 1.0f - (2.0f * (float)r + 1.0f) / 128.0f;

        int myid = (lane < len) ? (int)bl[j0 + lane] : 0;
        unsigned long long best = DINIT;
        int fcur = __shfl(myid, 0);
        int i3 = (b * NF + fcur) * 3;
        float4 E0 = face[i3], E1 = face[i3 + 1], FD = face[i3 + 2];
        for (int jj = 0; jj < len; ++jj) {
            int fn = __shfl(myid, (jj + 1) & 63);
            if (jj + 1 >= len) fn = fcur;
            int in3 = (b * NF + fn) * 3;
            float4 E0n = face[in3], E1n = face[in3 + 1], FDn = face[in3 + 2];
            float as = FD.x;
            // exact ref order: e = (bx-ax)*(py-ay) - (by-ay)*(px-ax)
            float u1 = E0.x * (py - E0.w);
            float u2 = E0.y * (px - E0.z);
            float e0 = u1 - u2;
            float u3 = E1.x * (py - E1.w);
            float u4 = E1.y * (px - E1.z);
            float e1 = u3 - u4;
            bool ok = (as > 0.0f) ? (e0 >= 0.0f && e1 >= 0.0f)
                                  : (e0 <= 0.0f && e1 <= 0.0f);
            if (__any(ok)) {
                float b0 = e0 / as; // true IEEE division, as in ref
                float b1 = e1 / as;
                float b2 = (1.0f - b0) - b1;
                float S = ((b0 / FD.y) + (b1 / FD.z)) + (b2 / FD.w);
                if (ok && b2 >= 0.0f && S > EPSF) {
                    float depth = 1.0f / fmaxf(S, EPSF);
                    unsigned long long pk =
                        ((unsigned long long)__float_as_uint(depth) << 32) |
                        (unsigned)fcur;
                    if (pk < best) best = pk;
                }
            }
            E0 = E0n; E1 = E1n; FD = FDn; fcur = fn;
        }
        if (best != DINIT) atomicMin(&dbuf[(size_t)bin * 64 + lane], best);
    }
}

__global__ __launch_bounds__(256) void k_shade(const float* __restrict__ verts,
                                               const int* __restrict__ faces,
                                               const float* __restrict__ vn,
                                               const unsigned long long* __restrict__ dbuf,
                                               float* __restrict__ out) {
    int i = blockIdx.x * 256 + threadIdx.x; // 0..NB*HW-1
    int b = i >> 14;
    int p = i & (HW - 1);
    int row = p >> 7;
    int col = p & 127;
    int tile = (row >> 3) * 16 + (col >> 3);
    int idx = (row & 7) * 8 + (col & 7);
    unsigned long long pk = dbuf[(size_t)(b * NTILE + tile) * 64 + idx];
    unsigned dbits = (unsigned)(pk >> 32);
    bool hit = dbits < 0x7F800000u;
    float cr = 255.0f, cg = 255.0f, cb = 255.0f, alpha = 0.0f;
    if (hit) {
        alpha = 1.0f;
        int f = (int)(unsigned)(pk & 0xFFFFFFFFull);
        float px = 1.0f - (2.0f * (float)col + 1.0f) / 128.0f;
        float py = 1.0f - (2.0f * (float)row + 1.0f) / 128.0f;
        int i0 = faces[f * 3 + 0];
        int i1 = faces[f * 3 + 1];
        int i2 = faces[f * 3 + 2];
        const float* wv = verts + (size_t)b * NV * 3;
        float v0x = wv[i0 * 3 + 0], v0y = wv[i0 * 3 + 1], v0z = wv[i0 * 3 + 2];
        float v1x = wv[i1 * 3 + 0], v1y = wv[i1 * 3 + 1], v1z = wv[i1 * 3 + 2];
        float v2x = wv[i2 * 3 + 0], v2y = wv[i2 * 3 + 1], v2z = wv[i2 * 3 + 2];
        float z0 = 2.0f - v0z, z1 = 2.0f - v1z, z2 = 2.0f - v2z;
        float a0x = (12.0f * (-v0x)) / z0, a0y = (12.0f * v0y) / z0;
        float a1x = (12.0f * (-v1x)) / z1, a1y = (12.0f * v1y) / z1;
        float a2x = (12.0f * (-v2x)) / z2, a2y = (12.0f * v2y) / z2;

        float t1 = (a1x - a0x) * (a2y - a0y);
        float t2 = (a1y - a0y) * (a2x - a0x);
        float ar = t1 - t2;
        ar = (fabsf(ar) < EPSF) ? EPSF : ar;
        float u1 = (a2x - a1x) * (py - a1y);
        float u2 = (a2y - a1y) * (px - a1x);
        float bb0 = (u1 - u2) / ar;
        float u3 = (a0x - a2x) * (py - a2y);
        float u4 = (a0y - a2y) * (px - a2x);
        float bb1 = (u3 - u4) / ar;
        float bb2 = (1.0f - bb0) - bb1;
        float w0 = bb0 / z0;
        float w1 = bb1 / z1;
        float w2 = bb2 / z2;
        float denom = ((w0 + w1) + w2) + EPSF;
        float pc0 = w0 / denom;
        float pc1 = w1 / denom;
        float pc2 = w2 / denom;

        float posx = (pc0 * v0x + pc1 * v1x) + pc2 * v2x;
        float posy = (pc0 * v0y + pc1 * v1y) + pc2 * v2y;
        float posz = (pc0 * v0z + pc1 * v1z) + pc2 * v2z;

        const float* vnb = vn + (size_t)b * NV * 3;
        float n0x = vnb[i0 * 3 + 0], n0y = vnb[i0 * 3 + 1], n0z = vnb[i0 * 3 + 2];
        float n1x = vnb[i1 * 3 + 0], n1y = vnb[i1 * 3 + 1], n1z = vnb[i1 * 3 + 2];
        float n2x = vnb[i2 * 3 + 0], n2y = vnb[i2 * 3 + 1], n2z = vnb[i2 * 3 + 2];
        float in0 = 1.0f / (sqrtf(n0x * n0x + n0y * n0y + n0z * n0z) + EPSF);
        float in1 = 1.0f / (sqrtf(n1x * n1x + n1y * n1y + n1z * n1z) + EPSF);
        float in2 = 1.0f / (sqrtf(n2x * n2x + n2y * n2y + n2z * n2z) + EPSF);
        n0x *= in0; n0y *= in0; n0z *= in0;
        n1x *= in1; n1y *= in1; n1z *= in1;
        n2x *= in2; n2y *= in2; n2z *= in2;
        float nx = (pc0 * n0x + pc1 * n1x) + pc2 * n2x;
        float ny = (pc0 * n0y + pc1 * n1y) + pc2 * n2y;
        float nz = (pc0 * n0z + pc1 * n1z) + pc2 * n2z;
        float inn = 1.0f / (sqrtf(nx * nx + ny * ny + nz * nz) + EPSF);
        nx *= inn; ny *= inn; nz *= inn;

        float lx = 0.0f - posx, ly = 1.0f - posy, lz = 3.0f - posz;
        float iln = 1.0f / (sqrtf(lx * lx + ly * ly + lz * lz) + EPSF);
        lx *= iln; ly *= iln; lz *= iln;
        float vx = 0.0f - posx, vy = 0.0f - posy, vz = 2.0f - posz;
        float ivn = 1.0f / (sqrtf(vx * vx + vy * vy + vz * vz) + EPSF);
        vx *= ivn; vy *= ivn; vz *= ivn;

        float ndl = nx * lx + ny * ly + nz * lz;
        float ndlr = fmaxf(ndl, 0.0f);
        float rx = 2.0f * ndl * nx - lx;
        float ry = 2.0f * ndl * ny - ly;
        float rz = 2.0f * ndl * nz - lz;
        float sc = fmaxf(rx * vx + ry * vy + rz * vz, 0.0f);
        float spec = 0.2f * 0.6f * powf(sc, 10.0f);
        float shade = 0.5f * 1.0f + 0.3f * 1.0f * ndlr;
        cr = ((142.0f / 255.0f) * shade + spec) * 255.0f;
        cg = ((179.0f / 255.0f) * shade + spec) * 255.0f;
        cb = ((247.0f / 255.0f) * shade + spec) * 255.0f;
    }
    float* img = out + (size_t)b * 3 * HW;
    img[0 * HW + p] = cr;
    img[1 * HW + p] = cg;
    img[2 * HW + p] = cb;
    out[(size_t)NB * 3 * HW + (size_t)b * HW + p] = alpha;
}

extern "C" void kernel_launch(void* const* d_in, const int* in_sizes, int n_in,
                              void* d_out, int out_size, void* d_ws, size_t ws_size,
                              hipStream_t stream) {
    const float* verts = (const float*)d_in[0]; // [NB, NV, 3]
    const int* faces = (const int*)d_in[1];     // [NF, 3]
    char* ws = (char*)d_ws;
    float* vn = (float*)(ws + 0);
    unsigned* ntask = (unsigned*)(ws + OFF_NTASK);
    float4* face = (float4*)(ws + OFF_FACE);
    float4* bboxf = (float4*)(ws + OFF_BBOX);
    unsigned* tasks = (unsigned*)(ws + OFF_TASK);
    unsigned* bins = (unsigned*)(ws + OFF_BINS);
    unsigned long long* dbuf = (unsigned long long*)(ws + OFF_DBUF);
    float* out = (float*)d_out;

    hipMemsetAsync(ws, 0, OFF_NTASK + 4, stream);              // vn + ntask
    hipMemsetAsync(ws + OFF_DBUF, 0xFF, NBIN * 64 * 8, stream); // depth sentinel
    k_face<<<(NFACE + 255) / 256, 256, 0, stream>>>(verts, faces, vn, face, bboxf);
    k_bin<<<NBIN, 256, 0, stream>>>(face, bboxf, bins, tasks, ntask);
    k_raster<<<NWAVE / 4, 256, 0, stream>>>(face, bins, tasks, ntask, dbuf);
    k_shade<<<(NB * HW) / 256, 256, 0, stream>>>(verts, faces, vn, dbuf, out);
}